// Round 2
// baseline (301.265 us; speedup 1.0000x reference)
//
#include <hip/hip_runtime.h>
#include <hip/hip_bf16.h>

#define D_MODEL 1024
#define SEQ 2048
#define NH 16
#define DKH 64

typedef __attribute__((ext_vector_type(8))) short bf16x8;
typedef __attribute__((ext_vector_type(4))) float f32x4;
typedef __attribute__((ext_vector_type(4))) int int4v;

__device__ inline short f2bf(float f) {
    __hip_bfloat16 h = __float2bfloat16(f);
    return __builtin_bit_cast(short, h);
}

// ---------------------------------------------------------------------------
// Kernel 1: W [K][N] fp32 -> Wt [N][K] bf16 (x3 weights via blockIdx.z)
// ---------------------------------------------------------------------------
__global__ void wt_kernel(const float* __restrict__ Wq, const float* __restrict__ Wk,
                          const float* __restrict__ Wv, short* __restrict__ Wt) {
    __shared__ float tile[32][33];
    const int z = blockIdx.z;
    const float* W = (z == 0) ? Wq : (z == 1) ? Wk : Wv;
    short* dst = Wt + (size_t)z * D_MODEL * D_MODEL;
    const int n0 = blockIdx.x * 32, k0 = blockIdx.y * 32;
    const int tx = threadIdx.x, ty = threadIdx.y;  // 32 x 8
    for (int i = 0; i < 4; ++i)
        tile[ty + 8 * i][tx] = W[(size_t)(k0 + ty + 8 * i) * D_MODEL + n0 + tx];
    __syncthreads();
    for (int i = 0; i < 4; ++i)
        dst[(size_t)(n0 + ty + 8 * i) * D_MODEL + k0 + tx] = f2bf(tile[tx][ty + 8 * i]);
}

// ---------------------------------------------------------------------------
// Kernel 2: projection GEMM. C = A @ W + b, A fp32 [4096][1024], Wt bf16 [N][K].
// z=0: qh (scaled by 0.125), z=1: kh, both [B,H,S,DK] bf16. z=2: vT [B,H,DK,S].
// 128x128 tile, BK=32, 4 waves (2x2), each wave 64x64 via 4x4 16x16x32 MFMA.
// ---------------------------------------------------------------------------
__global__ __launch_bounds__(256) void proj_kernel(
    const float* __restrict__ q, const float* __restrict__ k, const float* __restrict__ v,
    const short* __restrict__ Wt,
    const float* __restrict__ bq, const float* __restrict__ bk, const float* __restrict__ bv,
    short* __restrict__ qh, short* __restrict__ kh, short* __restrict__ vT) {
    constexpr int LS = 56;  // padded LDS row stride (112B, 16B-aligned, 2-way banks)
    __shared__ short sA[128][LS];
    __shared__ short sB[128][LS];

    const int z = blockIdx.z;
    const float* A = (z == 0) ? q : (z == 1) ? k : v;
    const short* B = Wt + (size_t)z * D_MODEL * D_MODEL;
    const float* bias = (z == 0) ? bq : (z == 1) ? bk : bv;
    short* dst = (z == 0) ? qh : (z == 1) ? kh : vT;

    const int m0 = blockIdx.y * 128;
    const int n0 = blockIdx.x * 128;
    const int tid = threadIdx.x;
    const int lane = tid & 63;
    const int w = tid >> 6;
    const int wr = w >> 1, wc = w & 1;
    const int lg = lane >> 4, ll = lane & 15;

    f32x4 acc[4][4] = {};

    const int arow = tid >> 1;
    const int aoff = (tid & 1) * 16;

    for (int kt = 0; kt < D_MODEL / 32; ++kt) {
        const int kk0 = kt * 32;
        __syncthreads();
        // stage A: 128x32 fp32 -> bf16 (fused convert)
        {
            const float* src = A + (size_t)(m0 + arow) * D_MODEL + kk0 + aoff;
            float4 f0 = *(const float4*)(src);
            float4 f1 = *(const float4*)(src + 4);
            float4 f2 = *(const float4*)(src + 8);
            float4 f3 = *(const float4*)(src + 12);
            bf16x8 p0, p1;
            p0[0] = f2bf(f0.x); p0[1] = f2bf(f0.y); p0[2] = f2bf(f0.z); p0[3] = f2bf(f0.w);
            p0[4] = f2bf(f1.x); p0[5] = f2bf(f1.y); p0[6] = f2bf(f1.z); p0[7] = f2bf(f1.w);
            p1[0] = f2bf(f2.x); p1[1] = f2bf(f2.y); p1[2] = f2bf(f2.z); p1[3] = f2bf(f2.w);
            p1[4] = f2bf(f3.x); p1[5] = f2bf(f3.y); p1[6] = f2bf(f3.z); p1[7] = f2bf(f3.w);
            *(bf16x8*)&sA[arow][aoff] = p0;
            *(bf16x8*)&sA[arow][aoff + 8] = p1;
        }
        // stage B: 128x32 bf16 straight copy
        for (int ss = 0; ss < 2; ++ss) {
            const int s = tid + ss * 256;
            const int r = s >> 2;
            const int c = (s & 3) * 8;
            *(int4v*)&sB[r][c] = *(const int4v*)(B + (size_t)(n0 + r) * D_MODEL + kk0 + c);
        }
        __syncthreads();

        bf16x8 af[4], bfr[4];
        for (int i = 0; i < 4; ++i)
            af[i] = *(const bf16x8*)&sA[wr * 64 + i * 16 + ll][lg * 8];
        for (int j = 0; j < 4; ++j)
            bfr[j] = *(const bf16x8*)&sB[wc * 64 + j * 16 + ll][lg * 8];
        for (int i = 0; i < 4; ++i)
            for (int j = 0; j < 4; ++j)
                acc[i][j] = __builtin_amdgcn_mfma_f32_16x16x32_bf16(af[i], bfr[j], acc[i][j], 0, 0, 0);
    }

    // epilogue: bias, optional scale, head-split layouts
    for (int j = 0; j < 4; ++j) {
        const int n = n0 + wc * 64 + j * 16 + ll;
        const float bn = bias[n];
        const int h = n >> 6, dk = n & 63;
        for (int i = 0; i < 4; ++i) {
            for (int rr = 0; rr < 4; ++rr) {
                const int m = m0 + wr * 64 + i * 16 + lg * 4 + rr;
                float val = acc[i][j][rr] + bn;
                if (z == 0) val *= 0.125f;  // fold 1/sqrt(DK) into qh
                const int b = m >> 11, s = m & 2047;
                size_t idx;
                if (z < 2) idx = (((size_t)(b * NH + h)) * SEQ + s) * DKH + dk;
                else       idx = (((size_t)(b * NH + h)) * DKH + dk) * SEQ + s;
                dst[idx] = f2bf(val);
            }
        }
    }
}

// ---------------------------------------------------------------------------
// Kernel 3: causal flash attention. Block = 256 threads = 4 waves, each wave
// owns 16 q-rows (Q-tile 64). K-tile 64. Online softmax in C-layout regs.
// ---------------------------------------------------------------------------
__global__ __launch_bounds__(256) void attn_kernel(
    const short* __restrict__ qh, const short* __restrict__ kh,
    const short* __restrict__ vT, float* __restrict__ out) {
    __shared__ short sK[64][72];        // [key][dk], padded
    __shared__ short sV[64][72];        // [dk][key], padded
    __shared__ short sP[4][16][72];     // per-wave P, [qrow][key], padded

    const int qt = blockIdx.x;
    const int bh = blockIdx.y;
    const int q0 = qt * 64;
    const int tid = threadIdx.x;
    const int w = tid >> 6;
    const int lane = tid & 63;
    const int lg = lane >> 4, ll = lane & 15;

    // Q fragments (scale pre-folded in projection)
    bf16x8 qf[2];
    {
        const short* src = qh + (((size_t)bh * SEQ) + q0 + w * 16 + ll) * DKH + lg * 8;
        qf[0] = *(const bf16x8*)(src);
        qf[1] = *(const bf16x8*)(src + 32);
    }

    f32x4 acc[4] = {};
    float m_i[4], l_i[4];
    for (int r = 0; r < 4; ++r) { m_i[r] = -1e30f; l_i[r] = 0.f; }

    const int ntiles = qt + 1;
    for (int t = 0; t < ntiles; ++t) {
        const int k0 = t * 64;
        __syncthreads();
        for (int ss = 0; ss < 2; ++ss) {
            const int s = tid + ss * 256;
            const int r = s >> 3;
            const int c = (s & 7) * 8;
            *(int4v*)&sK[r][c] = *(const int4v*)(kh + (((size_t)bh * SEQ) + k0 + r) * DKH + c);
            *(int4v*)&sV[r][c] = *(const int4v*)(vT + (((size_t)bh * DKH) + r) * SEQ + k0 + c);
        }
        __syncthreads();

        // scores: S = Q @ K^T (16x64 per wave)
        f32x4 sc[4] = {};
        for (int j = 0; j < 4; ++j) {
            bf16x8 kf0 = *(const bf16x8*)&sK[j * 16 + ll][lg * 8];
            bf16x8 kf1 = *(const bf16x8*)&sK[j * 16 + ll][lg * 8 + 32];
            sc[j] = __builtin_amdgcn_mfma_f32_16x16x32_bf16(qf[0], kf0, sc[j], 0, 0, 0);
            sc[j] = __builtin_amdgcn_mfma_f32_16x16x32_bf16(qf[1], kf1, sc[j], 0, 0, 0);
        }

        // causal mask — only the diagonal tile needs it
        if (t == ntiles - 1) {
            for (int j = 0; j < 4; ++j) {
                const int key = k0 + j * 16 + ll;
                for (int r = 0; r < 4; ++r) {
                    const int qrow = q0 + w * 16 + lg * 4 + r;
                    if (key > qrow) sc[j][r] = -1e30f;
                }
            }
        }

        // online softmax: rows live at (lane>>4)*4 + r, cols across 16-lane group
        float scale[4], tsum[4];
        for (int r = 0; r < 4; ++r) {
            float tm = fmaxf(fmaxf(sc[0][r], sc[1][r]), fmaxf(sc[2][r], sc[3][r]));
            tm = fmaxf(tm, __shfl_xor(tm, 1));
            tm = fmaxf(tm, __shfl_xor(tm, 2));
            tm = fmaxf(tm, __shfl_xor(tm, 4));
            tm = fmaxf(tm, __shfl_xor(tm, 8));
            const float mn = fmaxf(m_i[r], tm);
            scale[r] = __expf(m_i[r] - mn);
            m_i[r] = mn;
            float ts = 0.f;
            for (int j = 0; j < 4; ++j) {
                const float p = __expf(sc[j][r] - mn);
                sc[j][r] = p;
                ts += p;
            }
            ts += __shfl_xor(ts, 1);
            ts += __shfl_xor(ts, 2);
            ts += __shfl_xor(ts, 4);
            ts += __shfl_xor(ts, 8);
            tsum[r] = ts;
        }
        for (int r = 0; r < 4; ++r) l_i[r] = l_i[r] * scale[r] + tsum[r];
        for (int j = 0; j < 4; ++j)
            for (int r = 0; r < 4; ++r)
                acc[j][r] *= scale[r];

        // P -> LDS (C-layout scatter), then read back as A-fragments
        for (int j = 0; j < 4; ++j)
            for (int r = 0; r < 4; ++r)
                sP[w][lg * 4 + r][j * 16 + ll] = f2bf(sc[j][r]);

        bf16x8 pf0 = *(const bf16x8*)&sP[w][ll][lg * 8];
        bf16x8 pf1 = *(const bf16x8*)&sP[w][ll][lg * 8 + 32];
        for (int j = 0; j < 4; ++j) {
            bf16x8 vf0 = *(const bf16x8*)&sV[j * 16 + ll][lg * 8];
            bf16x8 vf1 = *(const bf16x8*)&sV[j * 16 + ll][lg * 8 + 32];
            acc[j] = __builtin_amdgcn_mfma_f32_16x16x32_bf16(pf0, vf0, acc[j], 0, 0, 0);
            acc[j] = __builtin_amdgcn_mfma_f32_16x16x32_bf16(pf1, vf1, acc[j], 0, 0, 0);
        }
    }

    // epilogue: O = acc / l, write [B,S,D] fp32
    const int b = bh >> 4, h = bh & 15;
    for (int j = 0; j < 4; ++j) {
        for (int r = 0; r < 4; ++r) {
            const int qrow = q0 + w * 16 + lg * 4 + r;
            const float o = acc[j][r] / l_i[r];
            out[((size_t)(b * SEQ + qrow)) * D_MODEL + h * DKH + j * 16 + ll] = o;
        }
    }
}

extern "C" void kernel_launch(void* const* d_in, const int* in_sizes, int n_in,
                              void* d_out, int out_size, void* d_ws, size_t ws_size,
                              hipStream_t stream) {
    const float* q  = (const float*)d_in[0];
    const float* k  = (const float*)d_in[1];
    const float* v  = (const float*)d_in[2];
    const float* Wq = (const float*)d_in[3];
    const float* bq = (const float*)d_in[4];
    const float* Wk = (const float*)d_in[5];
    const float* bk = (const float*)d_in[6];
    const float* Wv = (const float*)d_in[7];
    const float* bv = (const float*)d_in[8];
    float* out = (float*)d_out;

    // workspace layout (bf16 as short): Wt[3MK] | qh | kh | vT  (~30 MB)
    short* Wt = (short*)d_ws;
    short* qh = Wt + (size_t)3 * D_MODEL * D_MODEL;
    short* kh = qh + (size_t)2 * NH * SEQ * DKH;
    short* vT = kh + (size_t)2 * NH * SEQ * DKH;

    hipLaunchKernelGGL(wt_kernel, dim3(32, 32, 3), dim3(32, 8), 0, stream, Wq, Wk, Wv, Wt);
    hipLaunchKernelGGL(proj_kernel, dim3(8, 32, 3), dim3(256), 0, stream,
                       q, k, v, Wt, bq, bk, bv, qh, kh, vT);
    hipLaunchKernelGGL(attn_kernel, dim3(32, 32), dim3(256), 0, stream, qh, kh, vT, out);
}